// Round 3
// baseline (510.082 us; speedup 1.0000x reference)
//
#include <hip/hip_runtime.h>

// B=1024, H=56, J=64, N=56, I=64.
// t4[b,i,m,n] = sum_{k,j} x[b, m+k-1, j, n] * W2[i,k,j]   (zero-padded in h)
// y[b,i,m,(n+1)%56] = t4[b,i,m,n]*W1[i,0] + t4[b,i,(m-1)%56,n]*W1[i,1]
//
// n-roll handled by ROTATED B-fragments: lane column c reads LDS row (c+55)%56,
// so stores are aligned and no cross-lane shuffle is needed.
// Ring slots are compile-time: m0 = 4*it, 4 unrolled sub-steps.

#define HH 56
#define JJ 64
#define NN 56

// LDS: 56 n-rows x [slot(4) x j(64)] bf16, row stride 264 ushorts (528 B).
#define ROWE 264
#define SLOTE 64

typedef __attribute__((ext_vector_type(8))) short short8_t;
typedef __attribute__((ext_vector_type(4))) short short4_t;
typedef __attribute__((ext_vector_type(4))) float f32x4;

__device__ __forceinline__ unsigned short f2bf(float f) {
  union { float f; unsigned u; } v; v.f = f;
  return (unsigned short)((v.u + 0x7FFFu + ((v.u >> 16) & 1u)) >> 16);
}

#define BARRIER() do {                                   \
    asm volatile("s_waitcnt lgkmcnt(0)" ::: "memory");   \
    __builtin_amdgcn_s_barrier();                        \
    __builtin_amdgcn_sched_barrier(0);                   \
  } while (0)

__global__ __launch_bounds__(256, 5) void fused_conv_mix_kernel(
    const float* __restrict__ x, const float* __restrict__ W1,
    const float* __restrict__ W2, float* __restrict__ out) {
  __shared__ unsigned short lds[56 * ROWE];   // 29568 B -> 5 blocks/CU

  const int tid  = threadIdx.x;
  const int wave = tid >> 6;
  const int lane = tid & 63;
  const int lq   = lane & 15;
  const int lg   = lane >> 4;

  const int b = blockIdx.x;
  const float* __restrict__ xb   = x + (size_t)b * HH * JJ * NN;
  float* __restrict__       outb = out + (size_t)b * 64 * HH * NN;

  // ---- A fragments: W2[i,k,j] as 64 x 192 bf16, resident in VGPRs ----
  short8_t afrag[6];
  {
    const int i = 16 * wave + lq;
    #pragma unroll
    for (int s = 0; s < 6; ++s) {
      const int kk = s >> 1;
      const int j0 = (s & 1) * 32 + lg * 8;
      const float* p = W2 + ((size_t)i * 3 + kk) * 64 + j0;
      short8_t a;
      #pragma unroll
      for (int e = 0; e < 8; ++e) a[e] = (short)f2bf(p[e]);
      afrag[s] = a;
    }
  }

  // ---- W1 per-lane; output lane base (D rows i = ibase + r) ----
  const int ibase = 16 * wave + lg * 4;
  float w1a[4], w1b[4];
  #pragma unroll
  for (int r = 0; r < 4; ++r) {
    w1a[r] = W1[(ibase + r) * 2 + 0];
    w1b[r] = W1[(ibase + r) * 2 + 1];
  }
  float* const outl = outb + (size_t)ibase * HH * NN;   // r stride = HH*NN

  // ---- rotated B-row bases: column c=16t+lq reads row (c+55)%56 ----
  int rbase[4];
  #pragma unroll
  for (int t = 0; t < 4; ++t)
    rbase[t] = ((16 * t + lq + 55) % 56) * ROWE + lg * 8;

  // ---- staging coords: 224 workers, j-quad x n-quad ----
  const int sj  = (tid / 14) * 4;
  const int sn0 = (tid % 14) * 4;
  unsigned short* const sbase0 = &lds[(size_t)sn0 * ROWE + sj];

  auto issue = [&](int h, float4* R) {
    if (h <= HH && tid < 224) {
      if (h >= 0 && h < HH) {
        const float* p = xb + ((size_t)h * JJ + sj) * NN + sn0;
        R[0] = *(const float4*)(p);
        R[1] = *(const float4*)(p + NN);
        R[2] = *(const float4*)(p + 2 * NN);
        R[3] = *(const float4*)(p + 3 * NN);
      } else {
        float4 z = {0.f, 0.f, 0.f, 0.f};
        R[0] = z; R[1] = z; R[2] = z; R[3] = z;
      }
    }
  };

  auto putS = [&](int h, int slot, const float4* R) {
    if (h <= HH && tid < 224) {
      short4_t v0, v1, v2, v3;
      v0[0] = (short)f2bf(R[0].x); v0[1] = (short)f2bf(R[1].x); v0[2] = (short)f2bf(R[2].x); v0[3] = (short)f2bf(R[3].x);
      v1[0] = (short)f2bf(R[0].y); v1[1] = (short)f2bf(R[1].y); v1[2] = (short)f2bf(R[2].y); v1[3] = (short)f2bf(R[3].y);
      v2[0] = (short)f2bf(R[0].z); v2[1] = (short)f2bf(R[1].z); v2[2] = (short)f2bf(R[2].z); v2[3] = (short)f2bf(R[3].z);
      v3[0] = (short)f2bf(R[0].w); v3[1] = (short)f2bf(R[1].w); v3[2] = (short)f2bf(R[2].w); v3[3] = (short)f2bf(R[3].w);
      unsigned short* base = sbase0 + slot * SLOTE;
      *(short4_t*)(base)            = v0;
      *(short4_t*)(base + ROWE)     = v1;
      *(short4_t*)(base + 2 * ROWE) = v2;
      *(short4_t*)(base + 3 * ROWE) = v3;
    }
  };

  // one 3-tap GEMM step; slots are compile-time at every call site
  auto tap = [&](f32x4* acc, int kk, int slot) {
    #pragma unroll
    for (int half = 0; half < 2; ++half) {
      const int off = slot * SLOTE + half * 32;
      #pragma unroll
      for (int t = 0; t < 4; ++t) {
        const short8_t bf = *(const short8_t*)&lds[rbase[t] + off];
        acc[t] = __builtin_amdgcn_mfma_f32_16x16x32_bf16(afrag[2 * kk + half], bf, acc[t], 0, 0, 0);
      }
    }
  };
  auto compute = [&](f32x4* acc, int s0, int s1, int s2) {
    #pragma unroll
    for (int t = 0; t < 4; ++t) { acc[t][0] = 0.f; acc[t][1] = 0.f; acc[t][2] = 0.f; acc[t][3] = 0.f; }
    tap(acc, 0, s0); tap(acc, 1, s1); tap(acc, 2, s2);
  };

  // mix with W1 and store row m (aligned: lane column c = 16t+lq)
  auto mixstore = [&](int m, const f32x4* cur, const f32x4* prv) {
    float* const pr = outl + (size_t)m * NN;
    #pragma unroll
    for (int t = 0; t < 4; ++t) {
      const int c = 16 * t + lq;
      if (c < NN) {
        #pragma unroll
        for (int r = 0; r < 4; ++r)
          pr[(size_t)r * (HH * NN) + c] = cur[t][r] * w1a[r] + prv[t][r] * w1b[r];
      }
    }
  };

  f32x4 acc0[4], acc1[4];
  float4 R[4];

  // ---- prologue ----
  {
    float4 Ra[4], Rb[4], Rc[4];
    issue(54, Ra); issue(55, Rb); issue(56, Rc);
    putS(54, 2, Ra); putS(55, 3, Rb); putS(56, 0, Rc);
    __syncthreads();
    compute(acc1, 2, 3, 0);          // t4[55] = prev for m=0 (m-roll wrap)
    __syncthreads();
    issue(-1, Ra); issue(0, Rb); issue(1, Rc);
    putS(-1, 3, Ra); putS(0, 0, Rb); putS(1, 1, Rc);
    __syncthreads();
  }
  issue(2, R);

  // ---- main loop: 14 iterations x 4 unrolled sub-steps (slots static) ----
  #pragma unroll 1
  for (int it = 0; it < 14; ++it) {
    const int m0 = it * 4;
    // m0: cur=acc0 prev=acc1; taps h=m0-1..m0+1 -> slots 3,0,1
    compute(acc0, 3, 0, 1);
    putS(m0 + 2, 2, R);
    issue(m0 + 3, R);
    mixstore(m0, acc0, acc1);
    BARRIER();
    // m0+1: cur=acc1
    compute(acc1, 0, 1, 2);
    putS(m0 + 3, 3, R);
    issue(m0 + 4, R);
    mixstore(m0 + 1, acc1, acc0);
    BARRIER();
    // m0+2: cur=acc0
    compute(acc0, 1, 2, 3);
    putS(m0 + 4, 0, R);
    issue(m0 + 5, R);
    mixstore(m0 + 2, acc0, acc1);
    BARRIER();
    // m0+3: cur=acc1
    compute(acc1, 2, 3, 0);
    putS(m0 + 5, 1, R);
    issue(m0 + 6, R);
    mixstore(m0 + 3, acc1, acc0);
    BARRIER();
  }
}

extern "C" void kernel_launch(void* const* d_in, const int* in_sizes, int n_in,
                              void* d_out, int out_size, void* d_ws, size_t ws_size,
                              hipStream_t stream) {
  const float* x  = (const float*)d_in[0];
  const float* W1 = (const float*)d_in[1];
  const float* W2 = (const float*)d_in[2];
  float* out = (float*)d_out;
  fused_conv_mix_kernel<<<1024, 256, 0, stream>>>(x, W1, W2, out);
}

// Round 4
// 428.089 us; speedup vs baseline: 1.1915x; 1.1915x over previous
//
#include <hip/hip_runtime.h>

// B=1024, H=56, J=64, N=56, I=64.
// t4[b,i,m,n] = sum_{k,j} x[b, m+k-1, j, n] * W2[i,k,j]   (zero-padded in h)
// y[b,i,m,(n+1)%56] = t4[b,i,m,n]*W1[i,0] + t4[b,i,(m-1)%56,n]*W1[i,1]
//
// n-roll via rotated B-fragments (lane column c reads LDS row (c+55)%56).
// LDS j-chunks XOR-swizzled by g(n) = ((n>>2)^(n>>4))&3 on BOTH write and
// read (same involution) to break the 7-way ds_write bank conflict.
// Global-load pipeline depth 2 (Ra/Rb); stores issued after the barrier.

#define HH 56
#define JJ 64
#define NN 56

// LDS: [n(56 rows)][slot(4) x j(64)] bf16, row stride 264 ushorts (528 B).
#define ROWE 264
#define SLOTE 64

typedef __attribute__((ext_vector_type(8))) short short8_t;
typedef __attribute__((ext_vector_type(4))) short short4_t;
typedef __attribute__((ext_vector_type(4))) float f32x4;

__device__ __forceinline__ unsigned short f2bf(float f) {
  union { float f; unsigned u; } v; v.f = f;
  return (unsigned short)((v.u + 0x7FFFu + ((v.u >> 16) & 1u)) >> 16);
}

#define BARRIER() do {                                   \
    asm volatile("s_waitcnt lgkmcnt(0)" ::: "memory");   \
    __builtin_amdgcn_s_barrier();                        \
    __builtin_amdgcn_sched_barrier(0);                   \
  } while (0)

__global__ __launch_bounds__(256, 4) void fused_conv_mix_kernel(
    const float* __restrict__ x, const float* __restrict__ W1,
    const float* __restrict__ W2, float* __restrict__ out) {
  __shared__ unsigned short lds[56 * ROWE];   // 29568 B

  const int tid  = threadIdx.x;
  const int wave = tid >> 6;
  const int lane = tid & 63;
  const int lq   = lane & 15;
  const int lg   = lane >> 4;

  const int b = blockIdx.x;
  const float* __restrict__ xb   = x + (size_t)b * HH * JJ * NN;
  float* __restrict__       outb = out + (size_t)b * 64 * HH * NN;

  // ---- A fragments: W2[i,k,j] as 64 x 192 bf16, resident in VGPRs ----
  short8_t afrag[6];
  {
    const int i = 16 * wave + lq;
    #pragma unroll
    for (int s = 0; s < 6; ++s) {
      const int kk = s >> 1;
      const int j0 = (s & 1) * 32 + lg * 8;
      const float* p = W2 + ((size_t)i * 3 + kk) * 64 + j0;
      short8_t a;
      #pragma unroll
      for (int e = 0; e < 8; ++e) a[e] = (short)f2bf(p[e]);
      afrag[s] = a;
    }
  }

  // ---- W1 per-lane (D rows i = ibase + r) ----
  const int ibase = 16 * wave + lg * 4;
  float w1a[4], w1b[4];
  #pragma unroll
  for (int r = 0; r < 4; ++r) {
    w1a[r] = W1[(ibase + r) * 2 + 0];
    w1b[r] = W1[(ibase + r) * 2 + 1];
  }
  float* const outl = outb + (size_t)ibase * HH * NN;

  // ---- rotated + swizzled B-row bases: column c reads row (c+55)%56;
  //      j-chunk (8 ushort) index lg is XORed with g(row). ----
  int rbase[4];
  #pragma unroll
  for (int t = 0; t < 4; ++t) {
    const int row = (16 * t + lq + 55) % 56;
    const int gg  = ((row >> 2) ^ (row >> 4)) & 3;
    rbase[t] = row * ROWE + ((lg ^ gg) << 3);
  }

  // ---- staging coords: 224 workers = j-quad(16) x n-quad(14) ----
  const int jq = tid / 14;            // 0..15 (valid for tid<224)
  const int nq = tid - jq * 14;       // 0..13
  const int sj = jq * 4;              // global j for loads
  const int n0 = nq * 4;              // n row base
  const int gw = (nq ^ (nq >> 2)) & 3;                    // g(n), same for n0..n0+3
  const int jsw = (jq >> 3) * 32 + ((((jq >> 1) & 3) ^ gw) << 3) + (jq & 1) * 4;
  unsigned short* const sbase0 = &lds[(size_t)n0 * ROWE + jsw];

  auto issue = [&](int h, float4* R) {
    if (h <= HH && tid < 224) {
      if (h >= 0 && h < HH) {
        const float* p = xb + ((size_t)h * JJ + sj) * NN + n0;
        R[0] = *(const float4*)(p);
        R[1] = *(const float4*)(p + NN);
        R[2] = *(const float4*)(p + 2 * NN);
        R[3] = *(const float4*)(p + 3 * NN);
      } else {
        float4 z = {0.f, 0.f, 0.f, 0.f};
        R[0] = z; R[1] = z; R[2] = z; R[3] = z;
      }
    }
  };

  auto putS = [&](int h, int slot, const float4* R) {
    if (h <= HH && tid < 224) {
      short4_t v0, v1, v2, v3;
      v0[0] = (short)f2bf(R[0].x); v0[1] = (short)f2bf(R[1].x); v0[2] = (short)f2bf(R[2].x); v0[3] = (short)f2bf(R[3].x);
      v1[0] = (short)f2bf(R[0].y); v1[1] = (short)f2bf(R[1].y); v1[2] = (short)f2bf(R[2].y); v1[3] = (short)f2bf(R[3].y);
      v2[0] = (short)f2bf(R[0].z); v2[1] = (short)f2bf(R[1].z); v2[2] = (short)f2bf(R[2].z); v2[3] = (short)f2bf(R[3].z);
      v3[0] = (short)f2bf(R[0].w); v3[1] = (short)f2bf(R[1].w); v3[2] = (short)f2bf(R[2].w); v3[3] = (short)f2bf(R[3].w);
      unsigned short* base = sbase0 + slot * SLOTE;
      *(short4_t*)(base)            = v0;
      *(short4_t*)(base + ROWE)     = v1;
      *(short4_t*)(base + 2 * ROWE) = v2;
      *(short4_t*)(base + 3 * ROWE) = v3;
    }
  };

  auto tap = [&](f32x4* acc, int kk, int slot) {
    #pragma unroll
    for (int half = 0; half < 2; ++half) {
      const int off = slot * SLOTE + half * 32;
      #pragma unroll
      for (int t = 0; t < 4; ++t) {
        const short8_t bf = *(const short8_t*)&lds[rbase[t] + off];
        acc[t] = __builtin_amdgcn_mfma_f32_16x16x32_bf16(afrag[2 * kk + half], bf, acc[t], 0, 0, 0);
      }
    }
  };
  auto compute = [&](f32x4* acc, int s0, int s1, int s2) {
    #pragma unroll
    for (int t = 0; t < 4; ++t) { acc[t][0] = 0.f; acc[t][1] = 0.f; acc[t][2] = 0.f; acc[t][3] = 0.f; }
    tap(acc, 0, s0); tap(acc, 1, s1); tap(acc, 2, s2);
  };

  auto mixstore = [&](int m, const f32x4* cur, const f32x4* prv) {
    float* const pr = outl + (size_t)m * NN;
    #pragma unroll
    for (int t = 0; t < 4; ++t) {
      const int c = 16 * t + lq;
      if (c < NN) {
        #pragma unroll
        for (int r = 0; r < 4; ++r)
          pr[(size_t)r * (HH * NN) + c] = cur[t][r] * w1a[r] + prv[t][r] * w1b[r];
      }
    }
  };

  f32x4 acc0[4], acc1[4];
  float4 Ra[4], Rb[4];

  // ---- prologue ----
  {
    float4 Rc[4];
    issue(54, Ra); issue(55, Rb); issue(56, Rc);
    putS(54, 2, Ra); putS(55, 3, Rb); putS(56, 0, Rc);
    __syncthreads();
    compute(acc1, 2, 3, 0);          // t4[55] = prev for m=0 (m-roll wrap)
    __syncthreads();
    issue(-1, Ra); issue(0, Rb); issue(1, Rc);
    putS(-1, 3, Ra); putS(0, 0, Rb); putS(1, 1, Rc);
    __syncthreads();
    issue(2, Ra);                    // depth-2 load pipeline primed
    issue(3, Rb);
  }

  // ---- main loop: 14 x 4 substeps; slots & buffers static ----
  #pragma unroll 1
  for (int it = 0; it < 14; ++it) {
    const int m0 = it * 4;
    // m0: taps h=m0-1..m0+1 -> slots 3,0,1
    compute(acc0, 3, 0, 1);
    putS(m0 + 2, 2, Ra);   issue(m0 + 4, Ra);
    BARRIER();
    mixstore(m0, acc0, acc1);        // stores drain under next compute
    // m0+1
    compute(acc1, 0, 1, 2);
    putS(m0 + 3, 3, Rb);   issue(m0 + 5, Rb);
    BARRIER();
    mixstore(m0 + 1, acc1, acc0);
    // m0+2
    compute(acc0, 1, 2, 3);
    putS(m0 + 4, 0, Ra);   issue(m0 + 6, Ra);
    BARRIER();
    mixstore(m0 + 2, acc0, acc1);
    // m0+3
    compute(acc1, 2, 3, 0);
    putS(m0 + 5, 1, Rb);   issue(m0 + 7, Rb);
    BARRIER();
    mixstore(m0 + 3, acc1, acc0);
  }
}

extern "C" void kernel_launch(void* const* d_in, const int* in_sizes, int n_in,
                              void* d_out, int out_size, void* d_ws, size_t ws_size,
                              hipStream_t stream) {
  const float* x  = (const float*)d_in[0];
  const float* W1 = (const float*)d_in[1];
  const float* W2 = (const float*)d_in[2];
  float* out = (float*)d_out;
  fused_conv_mix_kernel<<<1024, 256, 0, stream>>>(x, W1, W2, out);
}